// Round 5
// baseline (142.388 us; speedup 1.0000x reference)
//
#include <hip/hip_runtime.h>
#include <hip/hip_fp16.h>
#include <math.h>

// GraphLearner: per-edge cosine similarity + sigmoid + straight-through threshold.
//   out[e] = let v = sigmoid(cos(f1,f2)/T) in (v <= 0.5 ? 0 : v)
//
// R13 = R12 resubmit (R12 bench died on container acquire, never ran).
// Defensive change: prep block 256 -> 128 threads so static LDS = 33.3 KB
// (safely under any per-block LDS limit; same 8 waves/CU occupancy).
//
// R12 rationale (R11 post-mortem: flight-depth doubling NEUTRAL -> L2-miss
// path THROUGHPUT-saturated at ~2.8 TB/s; FETCH budget 165MB = ~110MB table
// capacity misses (57% hit, at 4MiB-L2/6.4MB residency bound) + ~39MB
// exact-path fp32 (required for bit-exact gate sign) + ~16MB edge_index
// (compulsory). Edge kernel UNCHANGED R11 = structural ceiling.
//  - node_prep staged through LDS: old prep read 16 dwordx4/thread at 256-B
//    thread stride (64 lines/wave-instr, 16B used each -> L1 thrash). New:
//    fully-coalesced staging (1KB contig per wave-instr), LDS stride 65
//    floats (bank=(t+k)%32 -> 2-way = free), then IDENTICAL bit-exact FP
//    chain reads from LDS. Outputs bit-identical.

#define D 64
#define BLOCK 256
#define BLOCK_P 128   // prep block (128 rows staged, 33.3 KB LDS)
#define COS_EPS 1e-6f
#define TAU 6e-3f
#define LOG2E 1.4426950408889634f
#define LSTRIDE 65    // LDS row stride in floats: 65%32==1 -> bank=(t+k)%32

#define FMA4(A, X, Y) \
    A.x += X.x * Y.x; A.y += X.y * Y.y; A.z += X.z * Y.z; A.w += X.w * Y.w;

#define PAIRWISE8(E, O) \
    (((E.x + E.y) + (E.z + E.w)) + ((O.x + O.y) + (O.z + O.w)))

typedef int i32x4 __attribute__((ext_vector_type(4)));

__device__ __forceinline__ int dot4_i8(unsigned a, unsigned b, int acc) {
#if __has_builtin(__builtin_amdgcn_sdot4)
    return __builtin_amdgcn_sdot4(a, b, acc, false);
#else
    #pragma unroll
    for (int i = 0; i < 4; ++i) {
        int ai = (int)((signed char)((a >> (8 * i)) & 0xff));
        int bi = (int)((signed char)((b >> (8 * i)) & 0xff));
        acc += ai * bi;
    }
    return acc;
#endif
}

__device__ __forceinline__ float read_temperature(const int* temp_ptr) {
    int tbits = *temp_ptr;
    if (tbits >= 1 && tbits < (1 << 23)) return (float)tbits;  // int32 temperature
    union { int i; float f; } u; u.i = tbits; return u.f;      // float32 bits
}

// Exact fp32 recompute for one edge, bit-identical to the R3 kernel (passed).
// Normal (caching) loads: R10 proved nt here hurts.
__device__ __forceinline__ float exact_cos(
    const float* __restrict__ node_embs,
    const float* __restrict__ dnorm,
    int i0, int i1, int lane)
{
    const float4* __restrict__ r0 = (const float4*)(node_embs + (size_t)i0 * D);
    const float4* __restrict__ r1 = (const float4*)(node_embs + (size_t)i1 * D);
    float4 x0 = r0[lane];
    float4 x1 = r0[lane + 8];
    float4 y0 = r1[lane];
    float4 y1 = r1[lane + 8];
    float pp = ((x0.x * y0.x + x0.y * y0.y) + (x0.z * y0.z + x0.w * y0.w))
             + ((x1.x * y1.x + x1.y * y1.y) + (x1.z * y1.z + x1.w * y1.w));
    #pragma unroll
    for (int m = 1; m < 8; m <<= 1) pp += __shfl_xor(pp, m, 8);
    return pp / (dnorm[i0] * dnorm[i1]);
}

// Kernel P: LDS-staged coalesced load + fused per-node norm (bit-exact numpy
// order) + int8-quantized row. FP chain identical to R9/R11 (bit-identical).
__global__ __launch_bounds__(BLOCK_P) void node_prep_kernel(
    const float*   __restrict__ node_embs,
    float*         __restrict__ dnorm,
    float*         __restrict__ nscale,
    unsigned int*  __restrict__ q8,      // 16 dwords (64 int8) per node
    int n_nodes)
{
    __shared__ float lds[BLOCK_P * LSTRIDE];   // 128 rows x 65 floats = 33.3 KB

    int t = threadIdx.x;
    long long n_elems = (long long)n_nodes * D;
    long long base    = (long long)blockIdx.x * BLOCK_P * D;

    // Phase 1: stage 128 rows, fully coalesced (each wave-instr = 1 KB contig).
    // flat float index g = base + i*512 + 4t  ->  row r = i*8 + (t>>4),
    // col c = 4*(t&15).  Banks: (8i + (t>>4) + 4*(t&15)) % 32 -> 2-way, free.
    #pragma unroll
    for (int i = 0; i < 16; ++i) {
        long long g = base + (long long)i * (BLOCK_P * 4) + (long long)t * 4;
        float4 v = make_float4(0.f, 0.f, 0.f, 0.f);
        if (g < n_elems)                      // g%4==0, n_elems%4==0 -> safe
            v = *(const float4*)(node_embs + g);
        int r = i * 8 + (t >> 4);
        int c = (t & 15) * 4;
        float* p = &lds[r * LSTRIDE + c];
        p[0] = v.x; p[1] = v.y; p[2] = v.z; p[3] = v.w;
    }
    __syncthreads();

    int n = blockIdx.x * BLOCK_P + t;
    if (n >= n_nodes) return;

    // Phase 2: per-thread serial chain, reading own row from LDS.
    // Bank = (t + k) % 32 -> 2 lanes/bank per wave = conflict-free.
    const float* __restrict__ lr = &lds[t * LSTRIDE];
    float4 row[16];
    #pragma unroll
    for (int k = 0; k < 16; ++k)
        row[k] = make_float4(lr[4*k], lr[4*k+1], lr[4*k+2], lr[4*k+3]);

    // Clamped norm, bit-exact numpy pairwise order (unchanged from R2..R11).
    float4 z = make_float4(0.f, 0.f, 0.f, 0.f);
    float4 aE = z, aO = z;
    #pragma unroll
    for (int k = 0; k < 16; k += 2) {
        FMA4(aE, row[k], row[k])
        FMA4(aO, row[k + 1], row[k + 1])
    }
    float s = PAIRWISE8(aE, aO);
    float d = fmaxf(sqrtf(s), COS_EPS);
    dnorm[n] = d;
    float inv = 1.0f / d;

    // Row max |x| (order-free; only affects quantization, not exactness).
    float m0 = 0.f;
    #pragma unroll
    for (int k = 0; k < 16; ++k) {
        float4 a = row[k];
        m0 = fmaxf(m0, fmaxf(fmaxf(fabsf(a.x), fabsf(a.y)),
                             fmaxf(fabsf(a.z), fabsf(a.w))));
    }
    // q = rint(x * 127/m0)  (norm scale cancels);  decode scale on normalized
    // row: q * nscale ~= x*inv.  m0==0 -> all q=0, nscale=0 -> cos8=0 -> TAU
    // path -> exact recompute (safe).
    float kq = (m0 > 0.f) ? (127.0f / m0) : 0.f;
    nscale[n] = (m0 * inv) / 127.0f;

    unsigned int w[16];
    #pragma unroll
    for (int k = 0; k < 16; ++k) {
        float4 a = row[k];
        int q0 = (int)rintf(a.x * kq);
        int q1 = (int)rintf(a.y * kq);
        int q2 = (int)rintf(a.z * kq);
        int q3 = (int)rintf(a.w * kq);
        w[k] = (unsigned)(q0 & 255) | ((unsigned)(q1 & 255) << 8)
             | ((unsigned)(q2 & 255) << 16) | ((unsigned)(q3 & 255) << 24);
    }
    uint4* dst = (uint4*)(q8 + (size_t)n * 16);
    #pragma unroll
    for (int k = 0; k < 4; ++k)
        dst[k] = *(const uint4*)&w[k * 4];
}

// Kernel E: UNCHANGED R11 (at structural ceiling: miss path saturated).
// 8 lanes per group, 4 edges per group, int8 table (64 B rows).
__global__ __launch_bounds__(BLOCK) void GraphLearner_68513318306086_kernel(
    const float*        __restrict__ node_embs,
    const unsigned int* __restrict__ q8,
    const float*        __restrict__ nscale,
    const int*          __restrict__ edge_index,
    const float*        __restrict__ dnorm,
    const int*          __restrict__ temp_ptr,
    float*              __restrict__ out,
    int n_edges)
{
    int t    = blockIdx.x * BLOCK + threadIdx.x;
    int g    = t >> 3;              // group id: edges 4g .. 4g+3
    int lane = threadIdx.x & 7;
    int e0   = g * 4;
    if (e0 >= n_edges) return;

    int ia[4], ib[4];
    if (((n_edges & 3) == 0) && (e0 + 3 < n_edges)) {
        i32x4 v0 = *(const i32x4*)(edge_index + e0);
        i32x4 v1 = *(const i32x4*)(edge_index + n_edges + e0);
        ia[0] = v0.x; ia[1] = v0.y; ia[2] = v0.z; ia[3] = v0.w;
        ib[0] = v1.x; ib[1] = v1.y; ib[2] = v1.z; ib[3] = v1.w;
    } else {
        #pragma unroll
        for (int j = 0; j < 4; ++j) {
            int e = e0 + j; if (e > n_edges - 1) e = n_edges - 1;  // clamp (safe dup)
            ia[j] = edge_index[e];
            ib[j] = edge_index[n_edges + e];
        }
    }

    // 8 row gathers back-to-back (uint2 = 8 int8 per lane; 64 distinct 64-B
    // rows in flight per wave).
    const uint2* __restrict__ tab = (const uint2*)q8;   // 8 uint2 per node
    uint2 A[4], B[4];
    #pragma unroll
    for (int j = 0; j < 4; ++j) {
        A[j] = tab[(ia[j] << 3) + lane];
        B[j] = tab[(ib[j] << 3) + lane];
    }
    float sA[4], sB[4];
    #pragma unroll
    for (int j = 0; j < 4; ++j) {
        sA[j] = nscale[ia[j]];      // hot 400 KB table, L2-resident
        sB[j] = nscale[ib[j]];
    }

    // Exact integer dots (|sum| <= 64*127^2 < 2^24), butterfly allreduce in
    // int (order-independent, exact).
    int dd[4];
    #pragma unroll
    for (int j = 0; j < 4; ++j)
        dd[j] = dot4_i8(A[j].y, B[j].y, dot4_i8(A[j].x, B[j].x, 0));
    #pragma unroll
    for (int m = 1; m < 8; m <<= 1) {
        #pragma unroll
        for (int j = 0; j < 4; ++j) dd[j] += __shfl_xor(dd[j], m, 8);
    }

    float c0 = (float)dd[0] * (sA[0] * sB[0]);
    float c1 = (float)dd[1] * (sA[1] * sB[1]);
    float c2 = (float)dd[2] * (sA[2] * sB[2]);
    float c3 = (float)dd[3] * (sA[3] * sB[3]);

    // Quant dot err max < TAU -> sign safe outside TAU window; inside,
    // bit-exact fp32 recompute (identical to R3..R11, passed).
    if (fabsf(c0) < TAU) c0 = exact_cos(node_embs, dnorm, ia[0], ib[0], lane);
    if (fabsf(c1) < TAU) c1 = exact_cos(node_embs, dnorm, ia[1], ib[1], lane);
    if (fabsf(c2) < TAU) c2 = exact_cos(node_embs, dnorm, ia[2], ib[2], lane);
    if (fabsf(c3) < TAU) c3 = exact_cos(node_embs, dnorm, ia[3], ib[3], lane);

    if (lane < 4 && e0 + lane < n_edges) {
        float cosv = (lane == 0) ? c0 : (lane == 1) ? c1 : (lane == 2) ? c2 : c3;
        float T    = read_temperature(temp_ptr);
        float invT = __builtin_amdgcn_rcpf(T);      // T=1 -> exactly 1.0
        float x    = cosv * invT;
        // Gate on sign(x): v<=0.5 <=> x<=0 exactly (sigmoid monotone, sig(0)=0.5).
        float ex   = __builtin_amdgcn_exp2f(-x * LOG2E);
        float v    = __builtin_amdgcn_rcpf(1.0f + ex);
        out[e0 + lane] = (x <= 0.0f) ? 0.0f : v;
    }
}

// Fallback (ws too small): 8 lanes/edge fp32, inline norms (R3 fallback, passed).
__global__ __launch_bounds__(BLOCK) void edge_kernel_fused(
    const float* __restrict__ node_embs,
    const int*   __restrict__ edge_index,
    const int*   __restrict__ temp_ptr,
    float*       __restrict__ out,
    int n_edges)
{
    int t    = blockIdx.x * BLOCK + threadIdx.x;
    int e    = t >> 3;
    int lane = threadIdx.x & 7;
    if (e >= n_edges) return;

    int i0 = edge_index[e];
    int i1 = edge_index[n_edges + e];

    const float4* __restrict__ r0 = (const float4*)(node_embs + (size_t)i0 * D);
    const float4* __restrict__ r1 = (const float4*)(node_embs + (size_t)i1 * D);

    float4 x0 = r0[lane];
    float4 x1 = r0[lane + 8];
    float4 y0 = r1[lane];
    float4 y1 = r1[lane + 8];

    float p  = ((x0.x * y0.x + x0.y * y0.y) + (x0.z * y0.z + x0.w * y0.w))
             + ((x1.x * y1.x + x1.y * y1.y) + (x1.z * y1.z + x1.w * y1.w));
    float a  = ((x0.x * x0.x + x0.y * x0.y) + (x0.z * x0.z + x0.w * x0.w))
             + ((x1.x * x1.x + x1.y * x1.y) + (x1.z * x1.z + x1.w * x1.w));
    float b  = ((y0.x * y0.x + y0.y * y0.y) + (y0.z * y0.z + y0.w * y0.w))
             + ((y1.x * y1.x + y1.y * y1.y) + (y1.z * y1.z + y1.w * y1.w));

    #pragma unroll
    for (int m = 1; m < 8; m <<= 1) {
        p += __shfl_xor(p, m, 8);
        a += __shfl_xor(a, m, 8);
        b += __shfl_xor(b, m, 8);
    }

    if (lane == 0) {
        float T    = read_temperature(temp_ptr);
        float d1   = fmaxf(sqrtf(a), COS_EPS);
        float d2   = fmaxf(sqrtf(b), COS_EPS);
        float cosv = p / (d1 * d2);
        float v    = 1.0f / (1.0f + expf(-(cosv / T)));
        out[e] = (v <= 0.5f) ? 0.0f : v;
    }
}

extern "C" void kernel_launch(void* const* d_in, const int* in_sizes, int n_in,
                              void* d_out, int out_size, void* d_ws, size_t ws_size,
                              hipStream_t stream) {
    const float* node_embs  = (const float*)d_in[0];
    const int*   edge_index = (const int*)d_in[1];
    const int*   temp_ptr   = (const int*)d_in[2];
    float*       out        = (float*)d_out;

    int n_nodes = in_sizes[0] / D;      // node_embs is [N, 64]
    int n_elems = in_sizes[0];
    int n_edges = in_sizes[1] / 2;      // edge_index is [2, E]

    size_t q8_bytes = (size_t)n_elems;                            // 6.4 MB
    size_t need = q8_bytes + (size_t)n_nodes * 2 * sizeof(float); // + 800 KB

    if (ws_size >= need) {
        unsigned int* q8     = (unsigned int*)d_ws;
        float*        nscale = (float*)((char*)d_ws + q8_bytes);
        float*        dnorm  = nscale + n_nodes;

        int grid_n = (n_nodes + BLOCK_P - 1) / BLOCK_P;
        node_prep_kernel<<<grid_n, BLOCK_P, 0, stream>>>(node_embs, dnorm, nscale, q8, n_nodes);

        int n_groups = (n_edges + 3) / 4;          // 4 edges per 8-lane group
        long long n_threads = (long long)n_groups * 8;
        int grid_e = (int)((n_threads + BLOCK - 1) / BLOCK);
        GraphLearner_68513318306086_kernel<<<grid_e, BLOCK, 0, stream>>>(
            node_embs, q8, nscale, edge_index, dnorm, temp_ptr, out, n_edges);
    } else {
        int grid_e = (int)(((long long)n_edges * 8 + BLOCK - 1) / BLOCK);
        edge_kernel_fused<<<grid_e, BLOCK, 0, stream>>>(
            node_embs, edge_index, temp_ptr, out, n_edges);
    }
}

// Round 6
// 137.089 us; speedup vs baseline: 1.0387x; 1.0387x over previous
//
#include <hip/hip_runtime.h>
#include <hip/hip_fp16.h>
#include <math.h>

// GraphLearner: per-edge cosine similarity + sigmoid + straight-through threshold.
//   out[e] = let v = sigmoid(cos(f1,f2)/T) in (v <= 0.5 ? 0 : v)
//
// R14 = exact revert to R11 (best measured config, 138.3us; R13's LDS-staged
// prep was neutral-to-negative: old prep's 256-B-stride reads are L1-absorbed
// (16KB/wave working set), so staging had nothing to fix).
//
// Final structure rationale:
//  - Edge kernel at structural ceiling: L2-miss path saturated ~2.9 TB/s
//    (flight-depth doubling NEUTRAL (R11), nt NEGATIVE (R10)); FETCH 165MB =
//    ~110MB table capacity misses (57% hit, at 4MiB-L2/6.4MB residency bound)
//    + ~39MB exact-path fp32 (statistical minimum for int8 error envelope:
//    P(|cos|<TAU)~3.8%) + ~16MB compulsory edge_index stream.
//  - int8 table + per-node scale: exact integer dot (v_dot4_i32_i8, |sum| <
//    2^24), quant err max ~3e-3 < TAU=6e-3 -> sign-gate safe; |cos| < TAU ->
//    bit-exact fp32 recompute (R3 chain, passed).
//  - Prep at floor (R13 null). Residual ~80us of total-edge is fixed
//    harness/launch/reset overhead, invariant across R8-R13.

#define D 64
#define BLOCK 256
#define COS_EPS 1e-6f
#define TAU 6e-3f
#define LOG2E 1.4426950408889634f

#define FMA4(A, X, Y) \
    A.x += X.x * Y.x; A.y += X.y * Y.y; A.z += X.z * Y.z; A.w += X.w * Y.w;

#define PAIRWISE8(E, O) \
    (((E.x + E.y) + (E.z + E.w)) + ((O.x + O.y) + (O.z + O.w)))

typedef int i32x4 __attribute__((ext_vector_type(4)));

__device__ __forceinline__ int dot4_i8(unsigned a, unsigned b, int acc) {
#if __has_builtin(__builtin_amdgcn_sdot4)
    return __builtin_amdgcn_sdot4(a, b, acc, false);
#else
    #pragma unroll
    for (int i = 0; i < 4; ++i) {
        int ai = (int)((signed char)((a >> (8 * i)) & 0xff));
        int bi = (int)((signed char)((b >> (8 * i)) & 0xff));
        acc += ai * bi;
    }
    return acc;
#endif
}

__device__ __forceinline__ float read_temperature(const int* temp_ptr) {
    int tbits = *temp_ptr;
    if (tbits >= 1 && tbits < (1 << 23)) return (float)tbits;  // int32 temperature
    union { int i; float f; } u; u.i = tbits; return u.f;      // float32 bits
}

// Exact fp32 recompute for one edge, bit-identical to the R3 kernel (passed).
// Normal (caching) loads: R10 proved nt here hurts.
__device__ __forceinline__ float exact_cos(
    const float* __restrict__ node_embs,
    const float* __restrict__ dnorm,
    int i0, int i1, int lane)
{
    const float4* __restrict__ r0 = (const float4*)(node_embs + (size_t)i0 * D);
    const float4* __restrict__ r1 = (const float4*)(node_embs + (size_t)i1 * D);
    float4 x0 = r0[lane];
    float4 x1 = r0[lane + 8];
    float4 y0 = r1[lane];
    float4 y1 = r1[lane + 8];
    float pp = ((x0.x * y0.x + x0.y * y0.y) + (x0.z * y0.z + x0.w * y0.w))
             + ((x1.x * y1.x + x1.y * y1.y) + (x1.z * y1.z + x1.w * y1.w));
    #pragma unroll
    for (int m = 1; m < 8; m <<= 1) pp += __shfl_xor(pp, m, 8);
    return pp / (dnorm[i0] * dnorm[i1]);
}

// Kernel P: fused per-node norm (bit-exact numpy order) + int8-quantized row.
__global__ __launch_bounds__(BLOCK) void node_prep_kernel(
    const float*   __restrict__ node_embs,
    float*         __restrict__ dnorm,
    float*         __restrict__ nscale,
    unsigned int*  __restrict__ q8,      // 16 dwords (64 int8) per node
    int n_nodes)
{
    int n = blockIdx.x * BLOCK + threadIdx.x;
    if (n >= n_nodes) return;

    const float4* __restrict__ r = (const float4*)(node_embs + (size_t)n * D);

    float4 row[16];
    #pragma unroll
    for (int k = 0; k < 16; ++k) row[k] = r[k];

    // Clamped norm, bit-exact numpy pairwise order (unchanged from R2..R13).
    float4 z = make_float4(0.f, 0.f, 0.f, 0.f);
    float4 aE = z, aO = z;
    #pragma unroll
    for (int k = 0; k < 16; k += 2) {
        FMA4(aE, row[k], row[k])
        FMA4(aO, row[k + 1], row[k + 1])
    }
    float s = PAIRWISE8(aE, aO);
    float d = fmaxf(sqrtf(s), COS_EPS);
    dnorm[n] = d;
    float inv = 1.0f / d;

    // Row max |x| (order-free; only affects quantization, not exactness).
    float m0 = 0.f;
    #pragma unroll
    for (int k = 0; k < 16; ++k) {
        float4 a = row[k];
        m0 = fmaxf(m0, fmaxf(fmaxf(fabsf(a.x), fabsf(a.y)),
                             fmaxf(fabsf(a.z), fabsf(a.w))));
    }
    // q = rint(x * 127/m0)  (norm scale cancels);  decode scale on normalized
    // row: q * nscale ~= x*inv.  m0==0 -> all q=0, nscale=0 -> cos8=0 -> TAU
    // path -> exact recompute (safe).
    float kq = (m0 > 0.f) ? (127.0f / m0) : 0.f;
    nscale[n] = (m0 * inv) / 127.0f;

    unsigned int w[16];
    #pragma unroll
    for (int k = 0; k < 16; ++k) {
        float4 a = row[k];
        int q0 = (int)rintf(a.x * kq);
        int q1 = (int)rintf(a.y * kq);
        int q2 = (int)rintf(a.z * kq);
        int q3 = (int)rintf(a.w * kq);
        w[k] = (unsigned)(q0 & 255) | ((unsigned)(q1 & 255) << 8)
             | ((unsigned)(q2 & 255) << 16) | ((unsigned)(q3 & 255) << 24);
    }
    uint4* dst = (uint4*)(q8 + (size_t)n * 16);
    #pragma unroll
    for (int k = 0; k < 4; ++k)
        dst[k] = *(const uint4*)&w[k * 4];
}

// Kernel E: 8 lanes per group, 4 edges per group, int8 table (64 B rows).
// All loads/stores normal (caching) -- R10 proved nt regresses here.
__global__ __launch_bounds__(BLOCK) void GraphLearner_68513318306086_kernel(
    const float*        __restrict__ node_embs,
    const unsigned int* __restrict__ q8,
    const float*        __restrict__ nscale,
    const int*          __restrict__ edge_index,
    const float*        __restrict__ dnorm,
    const int*          __restrict__ temp_ptr,
    float*              __restrict__ out,
    int n_edges)
{
    int t    = blockIdx.x * BLOCK + threadIdx.x;
    int g    = t >> 3;              // group id: edges 4g .. 4g+3
    int lane = threadIdx.x & 7;
    int e0   = g * 4;
    if (e0 >= n_edges) return;

    int ia[4], ib[4];
    if (((n_edges & 3) == 0) && (e0 + 3 < n_edges)) {
        i32x4 v0 = *(const i32x4*)(edge_index + e0);
        i32x4 v1 = *(const i32x4*)(edge_index + n_edges + e0);
        ia[0] = v0.x; ia[1] = v0.y; ia[2] = v0.z; ia[3] = v0.w;
        ib[0] = v1.x; ib[1] = v1.y; ib[2] = v1.z; ib[3] = v1.w;
    } else {
        #pragma unroll
        for (int j = 0; j < 4; ++j) {
            int e = e0 + j; if (e > n_edges - 1) e = n_edges - 1;  // clamp (safe dup)
            ia[j] = edge_index[e];
            ib[j] = edge_index[n_edges + e];
        }
    }

    // 8 row gathers back-to-back (uint2 = 8 int8 per lane; 64 distinct 64-B
    // rows in flight per wave).
    const uint2* __restrict__ tab = (const uint2*)q8;   // 8 uint2 per node
    uint2 A[4], B[4];
    #pragma unroll
    for (int j = 0; j < 4; ++j) {
        A[j] = tab[(ia[j] << 3) + lane];
        B[j] = tab[(ib[j] << 3) + lane];
    }
    float sA[4], sB[4];
    #pragma unroll
    for (int j = 0; j < 4; ++j) {
        sA[j] = nscale[ia[j]];      // hot 400 KB table, L2-resident
        sB[j] = nscale[ib[j]];
    }

    // Exact integer dots (|sum| <= 64*127^2 < 2^24), butterfly allreduce in
    // int (order-independent, exact).
    int dd[4];
    #pragma unroll
    for (int j = 0; j < 4; ++j)
        dd[j] = dot4_i8(A[j].y, B[j].y, dot4_i8(A[j].x, B[j].x, 0));
    #pragma unroll
    for (int m = 1; m < 8; m <<= 1) {
        #pragma unroll
        for (int j = 0; j < 4; ++j) dd[j] += __shfl_xor(dd[j], m, 8);
    }

    float c0 = (float)dd[0] * (sA[0] * sB[0]);
    float c1 = (float)dd[1] * (sA[1] * sB[1]);
    float c2 = (float)dd[2] * (sA[2] * sB[2]);
    float c3 = (float)dd[3] * (sA[3] * sB[3]);

    // Quant dot err max < TAU -> sign safe outside TAU window; inside,
    // bit-exact fp32 recompute (identical to R3..R13, passed).
    if (fabsf(c0) < TAU) c0 = exact_cos(node_embs, dnorm, ia[0], ib[0], lane);
    if (fabsf(c1) < TAU) c1 = exact_cos(node_embs, dnorm, ia[1], ib[1], lane);
    if (fabsf(c2) < TAU) c2 = exact_cos(node_embs, dnorm, ia[2], ib[2], lane);
    if (fabsf(c3) < TAU) c3 = exact_cos(node_embs, dnorm, ia[3], ib[3], lane);

    if (lane < 4 && e0 + lane < n_edges) {
        float cosv = (lane == 0) ? c0 : (lane == 1) ? c1 : (lane == 2) ? c2 : c3;
        float T    = read_temperature(temp_ptr);
        float invT = __builtin_amdgcn_rcpf(T);      // T=1 -> exactly 1.0
        float x    = cosv * invT;
        // Gate on sign(x): v<=0.5 <=> x<=0 exactly (sigmoid monotone, sig(0)=0.5).
        float ex   = __builtin_amdgcn_exp2f(-x * LOG2E);
        float v    = __builtin_amdgcn_rcpf(1.0f + ex);
        out[e0 + lane] = (x <= 0.0f) ? 0.0f : v;
    }
}

// Fallback (ws too small): 8 lanes/edge fp32, inline norms (R3 fallback, passed).
__global__ __launch_bounds__(BLOCK) void edge_kernel_fused(
    const float* __restrict__ node_embs,
    const int*   __restrict__ edge_index,
    const int*   __restrict__ temp_ptr,
    float*       __restrict__ out,
    int n_edges)
{
    int t    = blockIdx.x * BLOCK + threadIdx.x;
    int e    = t >> 3;
    int lane = threadIdx.x & 7;
    if (e >= n_edges) return;

    int i0 = edge_index[e];
    int i1 = edge_index[n_edges + e];

    const float4* __restrict__ r0 = (const float4*)(node_embs + (size_t)i0 * D);
    const float4* __restrict__ r1 = (const float4*)(node_embs + (size_t)i1 * D);

    float4 x0 = r0[lane];
    float4 x1 = r0[lane + 8];
    float4 y0 = r1[lane];
    float4 y1 = r1[lane + 8];

    float p  = ((x0.x * y0.x + x0.y * y0.y) + (x0.z * y0.z + x0.w * y0.w))
             + ((x1.x * y1.x + x1.y * y1.y) + (x1.z * y1.z + x1.w * y1.w));
    float a  = ((x0.x * x0.x + x0.y * x0.y) + (x0.z * x0.z + x0.w * x0.w))
             + ((x1.x * x1.x + x1.y * x1.y) + (x1.z * x1.z + x1.w * x1.w));
    float b  = ((y0.x * y0.x + y0.y * y0.y) + (y0.z * y0.z + y0.w * y0.w))
             + ((y1.x * y1.x + y1.y * y1.y) + (y1.z * y1.z + y1.w * y1.w));

    #pragma unroll
    for (int m = 1; m < 8; m <<= 1) {
        p += __shfl_xor(p, m, 8);
        a += __shfl_xor(a, m, 8);
        b += __shfl_xor(b, m, 8);
    }

    if (lane == 0) {
        float T    = read_temperature(temp_ptr);
        float d1   = fmaxf(sqrtf(a), COS_EPS);
        float d2   = fmaxf(sqrtf(b), COS_EPS);
        float cosv = p / (d1 * d2);
        float v    = 1.0f / (1.0f + expf(-(cosv / T)));
        out[e] = (v <= 0.5f) ? 0.0f : v;
    }
}

extern "C" void kernel_launch(void* const* d_in, const int* in_sizes, int n_in,
                              void* d_out, int out_size, void* d_ws, size_t ws_size,
                              hipStream_t stream) {
    const float* node_embs  = (const float*)d_in[0];
    const int*   edge_index = (const int*)d_in[1];
    const int*   temp_ptr   = (const int*)d_in[2];
    float*       out        = (float*)d_out;

    int n_nodes = in_sizes[0] / D;      // node_embs is [N, 64]
    int n_elems = in_sizes[0];
    int n_edges = in_sizes[1] / 2;      // edge_index is [2, E]

    size_t q8_bytes = (size_t)n_elems;                            // 6.4 MB
    size_t need = q8_bytes + (size_t)n_nodes * 2 * sizeof(float); // + 800 KB

    if (ws_size >= need) {
        unsigned int* q8     = (unsigned int*)d_ws;
        float*        nscale = (float*)((char*)d_ws + q8_bytes);
        float*        dnorm  = nscale + n_nodes;

        int grid_n = (n_nodes + BLOCK - 1) / BLOCK;
        node_prep_kernel<<<grid_n, BLOCK, 0, stream>>>(node_embs, dnorm, nscale, q8, n_nodes);

        int n_groups = (n_edges + 3) / 4;          // 4 edges per 8-lane group
        long long n_threads = (long long)n_groups * 8;
        int grid_e = (int)((n_threads + BLOCK - 1) / BLOCK);
        GraphLearner_68513318306086_kernel<<<grid_e, BLOCK, 0, stream>>>(
            node_embs, q8, nscale, edge_index, dnorm, temp_ptr, out, n_edges);
    } else {
        int grid_e = (int)(((long long)n_edges * 8 + BLOCK - 1) / BLOCK);
        edge_kernel_fused<<<grid_e, BLOCK, 0, stream>>>(
            node_embs, edge_index, temp_ptr, out, n_edges);
    }
}